// Round 8
// baseline (298.343 us; speedup 1.0000x reference)
//
#include <hip/hip_runtime.h>
#include <hip/hip_bf16.h>
#include <stdint.h>

#define N_NODES 50000
#define N_EDGES 1600000
#define N_TOT   (N_EDGES + N_NODES)
#define NBKT      256
#define BKT_NODES 196   // 256*196 = 50176 >= 50000
#define BKT_CAP   7168  // mean 6468, sd ~79 -> +8.8 sigma; deterministic input
#define TILE      4096
#define EPT       16    // edges per thread in k_part
#define NGRP      12500 // node groups (4 nodes/block)
#define PROWS     (N_NODES + 1)   // panel rows incl. zero pad row

typedef unsigned short u16;
typedef __attribute__((ext_vector_type(8))) short short8;
typedef __attribute__((ext_vector_type(4))) float floatx4;

__device__ __forceinline__ float b2f(u16 u) {
    union { unsigned int i; float f; } v; v.i = ((unsigned int)u) << 16; return v.f;
}
__device__ __forceinline__ float asf(unsigned u) {
    union { unsigned int i; float f; } v; v.i = u; return v.f;
}
__device__ __forceinline__ u16 f2b(float f) {
    union { unsigned int i; float f; } v; v.f = f;
    unsigned int r = (v.i + 0x7FFFu + ((v.i >> 16) & 1u)) >> 16;
    return (u16)r;
}

// ---- dtype detection + bucket-counter zeroing ---------------------------
__global__ void k_detect(const unsigned* __restrict__ xw,
                         const unsigned* __restrict__ ew,
                         int* __restrict__ flags,
                         int* __restrict__ bktcnt) {
    __shared__ int cnt[2];
    int tid = threadIdx.x;
    bktcnt[tid] = 0;
    if (tid < 2) cnt[tid] = 0;
    __syncthreads();
    unsigned w = xw[tid];
    int e = (w >> 7) & 0xFF;
    int plaus = (e == 0) || (e >= 0x60 && e <= 0x9F);
    unsigned hw = ew[2 * tid + 1];
    atomicAdd(&cnt[0], plaus);
    atomicAdd(&cnt[1], hw == 0 ? 1 : 0);
    __syncthreads();
    if (tid == 0) {
        flags[0] = (cnt[0] < 160) ? 1 : 0;
        flags[1] = (cnt[1] > 250) ? 1 : 0;
    }
}

// ---- pass 1: partition edges into 256 dst-buckets (coalesced writes) ----
__global__ __launch_bounds__(256) void k_part(const int* __restrict__ ei,
                                              const int* __restrict__ flags,
                                              unsigned* __restrict__ pairs,
                                              int* __restrict__ bktcnt) {
    __shared__ unsigned pairsL[TILE];
    __shared__ unsigned char bktL[TILE];
    __shared__ int hist[NBKT], incl[NBKT], delta[NBKT];
    int tid = threadIdx.x;
    long base = (long)blockIdx.x * TILE;
    int i64 = flags[1];
    hist[tid] = 0;
    __syncthreads();

    int myb[EPT], myrank[EPT]; unsigned myp[EPT];
#pragma unroll
    for (int t = 0; t < EPT; t++) {
        long idx = base + t * 256 + tid;
        int b = -1; unsigned p = 0;
        if (idx < N_TOT) {
            int s, d;
            if (idx < N_EDGES) {
                if (i64) { s = ei[2 * idx]; d = ei[2 * (N_EDGES + idx)]; }
                else     { s = ei[idx];     d = ei[N_EDGES + idx]; }
            } else {
                s = d = (int)(idx - N_EDGES);   // self-loop
            }
            b = d / BKT_NODES;
            p = (unsigned)s | ((unsigned)(d - b * BKT_NODES) << 16);
        }
        myb[t] = b; myp[t] = p;
        myrank[t] = (b >= 0) ? atomicAdd(&hist[b], 1) : 0;
    }
    __syncthreads();

    int tot = hist[tid];
    incl[tid] = tot;
    __syncthreads();
    for (int o = 1; o < NBKT; o <<= 1) {
        int t2 = (tid >= o) ? incl[tid - o] : 0;
        __syncthreads();
        incl[tid] += t2;
        __syncthreads();
    }
    int excl = incl[tid] - tot;
    int gb = atomicAdd(&bktcnt[tid], tot);
    hist[tid]  = excl;
    delta[tid] = tid * BKT_CAP + gb - excl;
    __syncthreads();

#pragma unroll
    for (int t = 0; t < EPT; t++) {
        if (myb[t] >= 0) {
            int slot = hist[myb[t]] + myrank[t];
            pairsL[slot] = myp[t];
            bktL[slot]   = (unsigned char)myb[t];
        }
    }
    __syncthreads();
    int count = incl[NBKT - 1];
    for (int i = tid; i < count; i += 256) {
        int b = bktL[i];
        int pos = delta[b] + i;
        if (pos - b * BKT_CAP < BKT_CAP)
            pairs[pos] = pairsL[i];
    }
}

// ---- pass 2a: scan bucket counts -> bucket bases ------------------------
__global__ __launch_bounds__(256) void k_bktscan(const int* __restrict__ bktcnt,
                                                 int* __restrict__ bktbase) {
    __shared__ int s[NBKT];
    int tid = threadIdx.x;
    int v = bktcnt[tid];
    s[tid] = v;
    __syncthreads();
    for (int o = 1; o < NBKT; o <<= 1) {
        int t = (tid >= o) ? s[tid - o] : 0;
        __syncthreads();
        s[tid] += t;
        __syncthreads();
    }
    bktbase[tid] = s[tid] - v;
}

// ---- pass 2b: per bucket -> deg/rowstart/dinv + LDS csr, coalesced out --
__global__ __launch_bounds__(256) void k_bucket(const unsigned* __restrict__ pairs,
                                                const int* __restrict__ bktcnt,
                                                const int* __restrict__ bktbase,
                                                int* __restrict__ rowstart,
                                                int* __restrict__ deg,
                                                float* __restrict__ dinv,
                                                u16* __restrict__ csr) {
    __shared__ u16 csrL[BKT_CAP];
    __shared__ int degL[NBKT], curL[NBKT], scanT[NBKT];
    int b = blockIdx.x, tid = threadIdx.x;
    int cnt  = bktcnt[b];
    int base = bktbase[b];
    const unsigned* reg = pairs + (size_t)b * BKT_CAP;
    degL[tid] = 0;
    __syncthreads();
    for (int i = tid; i < cnt; i += 256)
        atomicAdd(&degL[reg[i] >> 16], 1);
    __syncthreads();
    int v = degL[tid];
    scanT[tid] = v;
    __syncthreads();
    for (int o = 1; o < NBKT; o <<= 1) {
        int t = (tid >= o) ? scanT[tid - o] : 0;
        __syncthreads();
        scanT[tid] += t;
        __syncthreads();
    }
    int excl = scanT[tid] - v;
    curL[tid] = excl;
    int n = b * BKT_NODES + tid;
    if (tid < BKT_NODES && n < N_NODES) {
        rowstart[n] = base + excl;
        deg[n]      = v;
        dinv[n]     = rsqrtf((float)v);
    }
    __syncthreads();
    for (int i = tid; i < cnt; i += 256) {
        unsigned p = reg[i];
        int slot = atomicAdd(&curL[p >> 16], 1);
        csrL[slot] = (u16)(p & 0xFFFFu);
    }
    __syncthreads();
    for (int i = tid; i < cnt; i += 256)
        csr[base + i] = csrL[i];
}

// ---- GEMM: h'[panel][row][32] = (A[M x 128] @ W[128 x NOUT]) * dinv[row]
// Panel-major output (32 feats/panel, PROWS rows incl. zero row for padding).
template<int NOUT, bool ADYN>
__global__ __launch_bounds__(256) void k_gemm(const void* __restrict__ A,
                                              const void* __restrict__ W,
                                              const float* __restrict__ dinv,
                                              u16* __restrict__ out, int M,
                                              const int* __restrict__ flags) {
    const int isf32 = flags[0];
    constexpr int LDW = 136;
    __shared__ __align__(16) u16 Wt[NOUT * LDW];
    int tid = threadIdx.x;
    // zero-pad row (read by agg for out-of-range edge slots)
    if (blockIdx.x == 0 && tid < NOUT)
        out[((size_t)((tid >> 5) * PROWS) + N_NODES) * 32 + (tid & 31)] = 0;
    const float* Wf = (const float*)W;
    const u16*   Wu = (const u16*)W;
    for (int idx = tid; idx < 128 * NOUT; idx += 256) {
        int k = idx / NOUT, n = idx % NOUT;
        Wt[n * LDW + k] = isf32 ? f2b(Wf[idx]) : Wu[idx];
    }
    __syncthreads();

    int wave = tid >> 6, lane = tid & 63;
    int quad = lane >> 4, l16 = lane & 15;
    int r0 = blockIdx.x * 64 + wave * 16;
    int r = r0 + l16; if (r >= M) r = M - 1;

    floatx4 acc[NOUT / 16];
#pragma unroll
    for (int i = 0; i < NOUT / 16; i++) acc[i] = (floatx4)(0.f);

#pragma unroll
    for (int ks = 0; ks < 4; ks++) {
        short8 a;
        if (ADYN && isf32) {
            const float* af = (const float*)A + (size_t)r * 128 + ks * 32 + quad * 8;
            float4 v0 = ((const float4*)af)[0];
            float4 v1 = ((const float4*)af)[1];
            a[0] = (short)f2b(v0.x); a[1] = (short)f2b(v0.y);
            a[2] = (short)f2b(v0.z); a[3] = (short)f2b(v0.w);
            a[4] = (short)f2b(v1.x); a[5] = (short)f2b(v1.y);
            a[6] = (short)f2b(v1.z); a[7] = (short)f2b(v1.w);
        } else {
            a = ((const short8*)((const u16*)A + (size_t)r * 128))[ks * 4 + quad];
        }
#pragma unroll
        for (int nt = 0; nt < NOUT / 16; nt++) {
            const short8* bp = (const short8*)&Wt[(nt * 16 + l16) * LDW + ks * 32 + quad * 8];
            acc[nt] = __builtin_amdgcn_mfma_f32_16x16x32_bf16(a, *bp, acc[nt], 0, 0, 0);
        }
    }
    float sc[4];
#pragma unroll
    for (int j = 0; j < 4; j++) {
        int row = r0 + quad * 4 + j;
        sc[j] = dinv[row < M ? row : 0];
    }
#pragma unroll
    for (int nt = 0; nt < NOUT / 16; nt++) {
        int col = nt * 16 + l16;
        int p = col >> 5, c = col & 31;
#pragma unroll
        for (int j = 0; j < 4; j++) {
            int row = r0 + quad * 4 + j;
            if (row < M)
                out[((size_t)(p * PROWS) + row) * 32 + c] = f2b(acc[nt][j] * sc[j]);
        }
    }
}

// accumulate one uint (2 bf16 feats) into a float2 (pk-add friendly)
#define ACCU(u, j) { acc[j].x += asf((u) << 16); acc[j].y += asf((u) & 0xFFFF0000u); }

// ---- Aggregation L1: panel pass (32 feats), 4-lane groups, uniform rounds
// blockIdx = panel*NGRP + group; zero-row padding kills divergence.
__global__ __launch_bounds__(256) void k_agg1(const u16* __restrict__ h,
                                              const u16* __restrict__ csr,
                                              const int* __restrict__ rowstart,
                                              const int* __restrict__ deg,
                                              const float* __restrict__ dinv,
                                              const void* __restrict__ bias,
                                              u16* __restrict__ out,
                                              const int* __restrict__ flags) {
    int wave = threadIdx.x >> 6, lane = threadIdx.x & 63;
    int gb = blockIdx.x % NGRP, panel = blockIdx.x / NGRP;
    int d = gb * 4 + wave;
    int grp = lane >> 2, l4 = lane & 3;
    int start = rowstart[d], dg = deg[d], end = start + dg;
    const u16* hp = h + (size_t)(panel * PROWS) * 32;
    float2 acc[4];
#pragma unroll
    for (int j = 0; j < 4; j++) acc[j] = make_float2(0.f, 0.f);

    int rounds = (dg + 31) >> 5;          // wave-uniform (deg same for wave)
    int e = start + grp;
    for (int r = 0; r < rounds; r++, e += 32) {
        int e1 = e + 16;
        int s0 = csr[e  < end ? e  : start];
        int s1 = csr[e1 < end ? e1 : start];
        s0 = (e  < end) ? s0 : N_NODES;    // zero row
        s1 = (e1 < end) ? s1 : N_NODES;
        uint4 v0 = ((const uint4*)(hp + (size_t)s0 * 32))[l4];
        uint4 v1 = ((const uint4*)(hp + (size_t)s1 * 32))[l4];
        ACCU(v0.x,0) ACCU(v0.y,1) ACCU(v0.z,2) ACCU(v0.w,3)
        ACCU(v1.x,0) ACCU(v1.y,1) ACCU(v1.z,2) ACCU(v1.w,3)
    }
#pragma unroll
    for (int j = 0; j < 4; j++) {
        acc[j].x += __shfl_xor(acc[j].x, 4);  acc[j].y += __shfl_xor(acc[j].y, 4);
        acc[j].x += __shfl_xor(acc[j].x, 8);  acc[j].y += __shfl_xor(acc[j].y, 8);
        acc[j].x += __shfl_xor(acc[j].x, 16); acc[j].y += __shfl_xor(acc[j].y, 16);
        acc[j].x += __shfl_xor(acc[j].x, 32); acc[j].y += __shfl_xor(acc[j].y, 32);
    }
    if (grp == 0) {                        // lane l4 holds feats panel*32+l4*8..+8
        int isf32 = flags[0];
        float dd = dinv[d];
        int fb = panel * 32 + l4 * 8;
        u16 r[8];
#pragma unroll
        for (int j = 0; j < 4; j++) {
            float bx = isf32 ? ((const float*)bias)[fb + 2 * j]
                             : b2f(((const u16*)bias)[fb + 2 * j]);
            float by = isf32 ? ((const float*)bias)[fb + 2 * j + 1]
                             : b2f(((const u16*)bias)[fb + 2 * j + 1]);
            float vx = acc[j].x * dd + bx;
            float vy = acc[j].y * dd + by;
            r[2 * j]     = f2b(vx > 0.f ? vx : 0.f);
            r[2 * j + 1] = f2b(vy > 0.f ? vy : 0.f);
        }
        uint4 o;
        o.x = r[0] | ((unsigned)r[1] << 16); o.y = r[2] | ((unsigned)r[3] << 16);
        o.z = r[4] | ((unsigned)r[5] << 16); o.w = r[6] | ((unsigned)r[7] << 16);
        ((uint4*)(out + (size_t)d * 128 + panel * 32))[l4] = o;
    }
}

// ---- Aggregation L2: panel pass (32 feats), fp32 out --------------------
__global__ __launch_bounds__(256) void k_agg2(const u16* __restrict__ h,
                                              const u16* __restrict__ csr,
                                              const int* __restrict__ rowstart,
                                              const int* __restrict__ deg,
                                              const float* __restrict__ dinv,
                                              const void* __restrict__ bias,
                                              float* __restrict__ out,
                                              const int* __restrict__ flags) {
    int wave = threadIdx.x >> 6, lane = threadIdx.x & 63;
    int gb = blockIdx.x % NGRP, panel = blockIdx.x / NGRP;
    int d = gb * 4 + wave;
    int grp = lane >> 2, l4 = lane & 3;
    int start = rowstart[d], dg = deg[d], end = start + dg;
    const u16* hp = h + (size_t)(panel * PROWS) * 32;
    float2 acc[4];
#pragma unroll
    for (int j = 0; j < 4; j++) acc[j] = make_float2(0.f, 0.f);

    int rounds = (dg + 31) >> 5;
    int e = start + grp;
    for (int r = 0; r < rounds; r++, e += 32) {
        int e1 = e + 16;
        int s0 = csr[e  < end ? e  : start];
        int s1 = csr[e1 < end ? e1 : start];
        s0 = (e  < end) ? s0 : N_NODES;
        s1 = (e1 < end) ? s1 : N_NODES;
        uint4 v0 = ((const uint4*)(hp + (size_t)s0 * 32))[l4];
        uint4 v1 = ((const uint4*)(hp + (size_t)s1 * 32))[l4];
        ACCU(v0.x,0) ACCU(v0.y,1) ACCU(v0.z,2) ACCU(v0.w,3)
        ACCU(v1.x,0) ACCU(v1.y,1) ACCU(v1.z,2) ACCU(v1.w,3)
    }
#pragma unroll
    for (int j = 0; j < 4; j++) {
        acc[j].x += __shfl_xor(acc[j].x, 4);  acc[j].y += __shfl_xor(acc[j].y, 4);
        acc[j].x += __shfl_xor(acc[j].x, 8);  acc[j].y += __shfl_xor(acc[j].y, 8);
        acc[j].x += __shfl_xor(acc[j].x, 16); acc[j].y += __shfl_xor(acc[j].y, 16);
        acc[j].x += __shfl_xor(acc[j].x, 32); acc[j].y += __shfl_xor(acc[j].y, 32);
    }
    if (grp == 0) {
        int isf32 = flags[0];
        float dd = dinv[d];
        int fb = panel * 32 + l4 * 8;
        float r[8];
#pragma unroll
        for (int j = 0; j < 4; j++) {
            float bx = isf32 ? ((const float*)bias)[fb + 2 * j]
                             : b2f(((const u16*)bias)[fb + 2 * j]);
            float by = isf32 ? ((const float*)bias)[fb + 2 * j + 1]
                             : b2f(((const u16*)bias)[fb + 2 * j + 1]);
            r[2 * j]     = acc[j].x * dd + bx;
            r[2 * j + 1] = acc[j].y * dd + by;
        }
        float4* op = (float4*)(out + (size_t)d * 64 + panel * 32 + l4 * 8);
        op[0] = make_float4(r[0], r[1], r[2], r[3]);
        op[1] = make_float4(r[4], r[5], r[6], r[7]);
    }
}

extern "C" void kernel_launch(void* const* d_in, const int* in_sizes, int n_in,
                              void* d_out, int out_size, void* d_ws, size_t ws_size,
                              hipStream_t stream) {
    const void* x  = d_in[0];              // [50000,128] fp32
    const int*  ei = (const int*)d_in[1];  // [2,1600000] int32/int64 (detected)
    const void* W1 = d_in[2];
    const void* b1 = d_in[3];
    const void* W2 = d_in[4];
    const void* b2 = d_in[5];
    float* out = (float*)d_out;            // [50000,64] fp32

    char* ws = (char*)d_ws;
    int*      flags    = (int*)(ws + 0);
    int*      bktcnt   = (int*)(ws + 1024);
    int*      bktbase  = (int*)(ws + 2048);
    int*      deg      = (int*)(ws + 4096);
    int*      rowstart = (int*)(ws + 204800);
    float*    dinv     = (float*)(ws + 405504);
    unsigned* pairs    = (unsigned*)(ws + 606208); // 7,340,032 B (dead after k_bucket)
    u16*      csr      = (u16*)(ws + 7946240);     // 3,300,000 B
    u16*      h1       = (u16*)(ws + 11247616);    // 4 panels * 50001*32*2 = 12,800,256 B
    u16*      out1     = (u16*)(ws + 24048640);    // 12,800,000 B
    u16*      h2       = (u16*)(ws + 606208);      // alias pairs: 2 panels = 6,400,128 B

    k_detect <<<1, 256, 0, stream>>>((const unsigned*)x, (const unsigned*)ei, flags, bktcnt);
    k_part   <<<(N_TOT + TILE - 1) / TILE, 256, 0, stream>>>(ei, flags, pairs, bktcnt);
    k_bktscan<<<1, 256, 0, stream>>>(bktcnt, bktbase);
    k_bucket <<<NBKT, 256, 0, stream>>>(pairs, bktcnt, bktbase, rowstart, deg, dinv, csr);

    k_gemm<128, true> <<<(N_NODES + 63) / 64, 256, 0, stream>>>(x, W1, dinv, h1, N_NODES, flags);
    k_agg1<<<4 * NGRP, 256, 0, stream>>>(h1, csr, rowstart, deg, dinv, b1, out1, flags);
    k_gemm<64, false> <<<(N_NODES + 63) / 64, 256, 0, stream>>>(out1, W2, dinv, h2, N_NODES, flags);
    k_agg2<<<2 * NGRP, 256, 0, stream>>>(h2, csr, rowstart, deg, dinv, b2, out, flags);
}

// Round 9
// 250.956 us; speedup vs baseline: 1.1888x; 1.1888x over previous
//
#include <hip/hip_runtime.h>
#include <hip/hip_bf16.h>
#include <stdint.h>

#define N_NODES 50000
#define N_EDGES 1600000
#define N_TOT   (N_EDGES + N_NODES)
#define NBKT      256
#define BKT_NODES 196   // 256*196 = 50176 >= 50000
#define BKT_CAP   7168  // mean 6468, sd ~79 -> +8.8 sigma; deterministic input
#define TILE      4096
#define EPT       16    // edges per thread in k_part
#define ZROW      N_NODES   // zero-padding row index in h buffers

typedef unsigned short u16;
typedef __attribute__((ext_vector_type(8))) short short8;
typedef __attribute__((ext_vector_type(4))) float floatx4;

__device__ __forceinline__ float b2f(u16 u) {
    union { unsigned int i; float f; } v; v.i = ((unsigned int)u) << 16; return v.f;
}
__device__ __forceinline__ float asf(unsigned u) {
    union { unsigned int i; float f; } v; v.i = u; return v.f;
}
__device__ __forceinline__ u16 f2b(float f) {
    union { unsigned int i; float f; } v; v.f = f;
    unsigned int r = (v.i + 0x7FFFu + ((v.i >> 16) & 1u)) >> 16;
    return (u16)r;
}

// ---- pass 1: partition edges into 256 dst-buckets (coalesced writes) ----
// Self-detects int64 edge_index (all blocks sample the same L2-hot words);
// block 0 additionally writes flags (fp32-input + i64) for later kernels.
__global__ __launch_bounds__(256) void k_part(const int* __restrict__ ei,
                                              const unsigned* __restrict__ xw,
                                              int* __restrict__ flags,
                                              unsigned* __restrict__ pairs,
                                              int* __restrict__ bktcnt) {
    __shared__ unsigned pairsL[TILE];
    __shared__ unsigned char bktL[TILE];
    __shared__ int hist[NBKT], incl[NBKT], delta[NBKT];
    __shared__ int zc, pc;
    int tid = threadIdx.x;
    long base = (long)blockIdx.x * TILE;
    hist[tid] = 0;
    if (tid == 0) { zc = 0; pc = 0; }
    __syncthreads();
    // i64 detection: odd 32-bit words of first 256 edge slots are all zero
    // iff int64 (values < 50000). Same sample for every block -> consistent.
    unsigned hw = ((const unsigned*)ei)[2 * tid + 1];
    atomicAdd(&zc, hw == 0 ? 1 : 0);
    if (blockIdx.x == 0) {
        unsigned w = xw[tid];
        int ex = (w >> 7) & 0xFF;     // bf16 exponent field if x were bf16
        atomicAdd(&pc, ((ex == 0) || (ex >= 0x60 && ex <= 0x9F)) ? 1 : 0);
    }
    __syncthreads();
    int i64 = zc > 250;
    if (blockIdx.x == 0 && tid == 0) {
        flags[0] = (pc < 160) ? 1 : 0;   // fp32 inputs
        flags[1] = i64;
    }

    int myb[EPT], myrank[EPT]; unsigned myp[EPT];
#pragma unroll
    for (int t = 0; t < EPT; t++) {
        long idx = base + t * 256 + tid;
        int b = -1; unsigned p = 0;
        if (idx < N_TOT) {
            int s, d;
            if (idx < N_EDGES) {
                if (i64) { s = ei[2 * idx]; d = ei[2 * (N_EDGES + idx)]; }
                else     { s = ei[idx];     d = ei[N_EDGES + idx]; }
            } else {
                s = d = (int)(idx - N_EDGES);   // self-loop
            }
            b = d / BKT_NODES;
            p = (unsigned)s | ((unsigned)(d - b * BKT_NODES) << 16);
        }
        myb[t] = b; myp[t] = p;
        myrank[t] = (b >= 0) ? atomicAdd(&hist[b], 1) : 0;
    }
    __syncthreads();

    int tot = hist[tid];
    incl[tid] = tot;
    __syncthreads();
    for (int o = 1; o < NBKT; o <<= 1) {
        int t2 = (tid >= o) ? incl[tid - o] : 0;
        __syncthreads();
        incl[tid] += t2;
        __syncthreads();
    }
    int excl = incl[tid] - tot;
    int gb = atomicAdd(&bktcnt[tid], tot);
    hist[tid]  = excl;
    delta[tid] = tid * BKT_CAP + gb - excl;
    __syncthreads();

#pragma unroll
    for (int t = 0; t < EPT; t++) {
        if (myb[t] >= 0) {
            int slot = hist[myb[t]] + myrank[t];
            pairsL[slot] = myp[t];
            bktL[slot]   = (unsigned char)myb[t];
        }
    }
    __syncthreads();
    int count = incl[NBKT - 1];
    for (int i = tid; i < count; i += 256) {
        int b = bktL[i];
        int pos = delta[b] + i;
        if (pos - b * BKT_CAP < BKT_CAP)
            pairs[pos] = pairsL[i];
    }
}

// ---- pass 2: per bucket -> deg/rowstart/dinv + LDS csr, coalesced out ---
// Inline scan of bucket counts (replaces separate k_bktscan dispatch).
__global__ __launch_bounds__(256) void k_bucket(const unsigned* __restrict__ pairs,
                                                const int* __restrict__ bktcnt,
                                                int* __restrict__ rowstart,
                                                int* __restrict__ deg,
                                                float* __restrict__ dinv,
                                                u16* __restrict__ csr) {
    __shared__ u16 csrL[BKT_CAP];
    __shared__ int degL[NBKT], curL[NBKT], scanT[NBKT];
    int b = blockIdx.x, tid = threadIdx.x;
    // inline exclusive scan over all bucket counts (redundant per block, cheap)
    int cv = bktcnt[tid];
    scanT[tid] = cv;
    __syncthreads();
    for (int o = 1; o < NBKT; o <<= 1) {
        int t = (tid >= o) ? scanT[tid - o] : 0;
        __syncthreads();
        scanT[tid] += t;
        __syncthreads();
    }
    int cnt  = bktcnt[b];
    int base = scanT[b] - cnt;      // exclusive prefix for this bucket
    __syncthreads();                // scanT reused below

    const unsigned* reg = pairs + (size_t)b * BKT_CAP;
    degL[tid] = 0;
    __syncthreads();
    for (int i = tid; i < cnt; i += 256)
        atomicAdd(&degL[reg[i] >> 16], 1);
    __syncthreads();
    int v = degL[tid];
    scanT[tid] = v;
    __syncthreads();
    for (int o = 1; o < NBKT; o <<= 1) {
        int t = (tid >= o) ? scanT[tid - o] : 0;
        __syncthreads();
        scanT[tid] += t;
        __syncthreads();
    }
    int excl = scanT[tid] - v;
    curL[tid] = excl;
    int n = b * BKT_NODES + tid;
    if (tid < BKT_NODES && n < N_NODES) {
        rowstart[n] = base + excl;
        deg[n]      = v;
        dinv[n]     = rsqrtf((float)v);
    }
    __syncthreads();
    for (int i = tid; i < cnt; i += 256) {
        unsigned p = reg[i];
        int slot = atomicAdd(&curL[p >> 16], 1);
        csrL[slot] = (u16)(p & 0xFFFFu);
    }
    __syncthreads();
    for (int i = tid; i < cnt; i += 256)
        csr[base + i] = csrL[i];
}

// ---- GEMM: out[M x NOUT] = (A[M x 128] @ W[128 x NOUT]) * dinv[row] -----
// Row-major bf16 out, plus zero row at index M (agg padding target).
template<int NOUT, bool ADYN>
__global__ __launch_bounds__(256) void k_gemm(const void* __restrict__ A,
                                              const void* __restrict__ W,
                                              const float* __restrict__ dinv,
                                              u16* __restrict__ out, int M,
                                              const int* __restrict__ flags) {
    const int isf32 = flags[0];
    constexpr int LDW = 136;
    __shared__ __align__(16) u16 Wt[NOUT * LDW];
    int tid = threadIdx.x;
    if (blockIdx.x == 0 && tid < NOUT)
        out[(size_t)M * NOUT + tid] = 0;          // zero-pad row
    const float* Wf = (const float*)W;
    const u16*   Wu = (const u16*)W;
    for (int idx = tid; idx < 128 * NOUT; idx += 256) {
        int k = idx / NOUT, n = idx % NOUT;
        Wt[n * LDW + k] = isf32 ? f2b(Wf[idx]) : Wu[idx];
    }
    __syncthreads();

    int wave = tid >> 6, lane = tid & 63;
    int quad = lane >> 4, l16 = lane & 15;
    int r0 = blockIdx.x * 64 + wave * 16;
    int r = r0 + l16; if (r >= M) r = M - 1;

    floatx4 acc[NOUT / 16];
#pragma unroll
    for (int i = 0; i < NOUT / 16; i++) acc[i] = (floatx4)(0.f);

#pragma unroll
    for (int ks = 0; ks < 4; ks++) {
        short8 a;
        if (ADYN && isf32) {
            const float* af = (const float*)A + (size_t)r * 128 + ks * 32 + quad * 8;
            float4 v0 = ((const float4*)af)[0];
            float4 v1 = ((const float4*)af)[1];
            a[0] = (short)f2b(v0.x); a[1] = (short)f2b(v0.y);
            a[2] = (short)f2b(v0.z); a[3] = (short)f2b(v0.w);
            a[4] = (short)f2b(v1.x); a[5] = (short)f2b(v1.y);
            a[6] = (short)f2b(v1.z); a[7] = (short)f2b(v1.w);
        } else {
            a = ((const short8*)((const u16*)A + (size_t)r * 128))[ks * 4 + quad];
        }
#pragma unroll
        for (int nt = 0; nt < NOUT / 16; nt++) {
            const short8* bp = (const short8*)&Wt[(nt * 16 + l16) * LDW + ks * 32 + quad * 8];
            acc[nt] = __builtin_amdgcn_mfma_f32_16x16x32_bf16(a, *bp, acc[nt], 0, 0, 0);
        }
    }
    float sc[4];
#pragma unroll
    for (int j = 0; j < 4; j++) {
        int row = r0 + quad * 4 + j;
        sc[j] = dinv[row < M ? row : 0];
    }
#pragma unroll
    for (int nt = 0; nt < NOUT / 16; nt++) {
#pragma unroll
        for (int j = 0; j < 4; j++) {
            int row = r0 + quad * 4 + j;
            if (row < M)
                out[(size_t)row * NOUT + nt * 16 + l16] = f2b(acc[nt][j] * sc[j]);
        }
    }
}

// accumulate one uint (2 bf16 feats) into a float2 (pk-add friendly)
#define ACCU(u, j) { acc[j].x += asf((u) << 16); acc[j].y += asf((u) & 0xFFFF0000u); }
#define ACC8(q0, q1) { ACCU(q0.x,0) ACCU(q0.y,1) ACCU(q0.z,2) ACCU(q0.w,3) \
                       ACCU(q1.x,4) ACCU(q1.y,5) ACCU(q1.z,6) ACCU(q1.w,7) }
#define ACC4(q)      { ACCU(q.x,0) ACCU(q.y,1) ACCU(q.z,2) ACCU(q.w,3) }

// ---- Aggregation L1: 8-lane groups, 32 B/lane, uniform 8-edge rounds,
// depth-2 software pipeline (4 dwordx4 in flight), zero-row padding.
__global__ __launch_bounds__(256) void k_agg1(const u16* __restrict__ h,
                                              const u16* __restrict__ csr,
                                              const int* __restrict__ rowstart,
                                              const int* __restrict__ deg,
                                              const float* __restrict__ dinv,
                                              const void* __restrict__ bias,
                                              u16* __restrict__ out,
                                              const int* __restrict__ flags) {
    int wave = threadIdx.x >> 6, lane = threadIdx.x & 63;
    int d = blockIdx.x * 4 + wave;               // 12500 blocks * 4 = exact
    int oct = lane >> 3, l8 = lane & 7;
    int start = rowstart[d], dg = deg[d], end = start + dg;
    int rounds = (dg + 7) >> 3;                  // wave-uniform
    float2 acc[8];
#pragma unroll
    for (int j = 0; j < 8; j++) acc[j] = make_float2(0.f, 0.f);

    int e = start + oct;
    int sA = (e < end) ? csr[e] : ZROW;
    const uint4* pA = (const uint4*)(h + (size_t)sA * 128) + l8 * 2;
    uint4 a0 = pA[0], a1 = pA[1];
    e += 8;
    int sB = (e < end) ? csr[e] : ZROW;
    const uint4* pB = (const uint4*)(h + (size_t)sB * 128) + l8 * 2;
    uint4 b0 = pB[0], b1 = pB[1];
    for (int r = 2; r < rounds; r++) {
        e += 8;
        int sC = (e < end) ? csr[e] : ZROW;
        const uint4* pC = (const uint4*)(h + (size_t)sC * 128) + l8 * 2;
        uint4 c0 = pC[0], c1 = pC[1];
        ACC8(a0, a1)
        a0 = b0; a1 = b1; b0 = c0; b1 = c1;
    }
    ACC8(a0, a1)
    ACC8(b0, b1)
#pragma unroll
    for (int j = 0; j < 8; j++) {
        acc[j].x += __shfl_xor(acc[j].x, 8);  acc[j].y += __shfl_xor(acc[j].y, 8);
        acc[j].x += __shfl_xor(acc[j].x, 16); acc[j].y += __shfl_xor(acc[j].y, 16);
        acc[j].x += __shfl_xor(acc[j].x, 32); acc[j].y += __shfl_xor(acc[j].y, 32);
    }
    if (oct == 0) {                            // lane l8 holds feats [l8*16, +16)
        int isf32 = flags[0];
        float dd = dinv[d];
        u16 r[16];
#pragma unroll
        for (int j = 0; j < 8; j++) {
            float bx = isf32 ? ((const float*)bias)[l8 * 16 + 2 * j]
                             : b2f(((const u16*)bias)[l8 * 16 + 2 * j]);
            float by = isf32 ? ((const float*)bias)[l8 * 16 + 2 * j + 1]
                             : b2f(((const u16*)bias)[l8 * 16 + 2 * j + 1]);
            float vx = acc[j].x * dd + bx;
            float vy = acc[j].y * dd + by;
            r[2 * j]     = f2b(vx > 0.f ? vx : 0.f);
            r[2 * j + 1] = f2b(vy > 0.f ? vy : 0.f);
        }
        uint4 o0, o1;
        o0.x = r[0] | ((unsigned)r[1] << 16);  o0.y = r[2] | ((unsigned)r[3] << 16);
        o0.z = r[4] | ((unsigned)r[5] << 16);  o0.w = r[6] | ((unsigned)r[7] << 16);
        o1.x = r[8] | ((unsigned)r[9] << 16);  o1.y = r[10] | ((unsigned)r[11] << 16);
        o1.z = r[12] | ((unsigned)r[13] << 16); o1.w = r[14] | ((unsigned)r[15] << 16);
        ((uint4*)(out + (size_t)d * 128))[l8 * 2]     = o0;
        ((uint4*)(out + (size_t)d * 128))[l8 * 2 + 1] = o1;
    }
}

// ---- Aggregation L2: 8-lane groups, 16 B/lane, same pipeline, fp32 out --
__global__ __launch_bounds__(256) void k_agg2(const u16* __restrict__ h,
                                              const u16* __restrict__ csr,
                                              const int* __restrict__ rowstart,
                                              const int* __restrict__ deg,
                                              const float* __restrict__ dinv,
                                              const void* __restrict__ bias,
                                              float* __restrict__ out,
                                              const int* __restrict__ flags) {
    int wave = threadIdx.x >> 6, lane = threadIdx.x & 63;
    int d = blockIdx.x * 4 + wave;
    int oct = lane >> 3, l8 = lane & 7;
    int start = rowstart[d], dg = deg[d], end = start + dg;
    int rounds = (dg + 7) >> 3;
    float2 acc[4];
#pragma unroll
    for (int j = 0; j < 4; j++) acc[j] = make_float2(0.f, 0.f);

    int e = start + oct;
    int sA = (e < end) ? csr[e] : ZROW;
    uint4 a0 = ((const uint4*)(h + (size_t)sA * 64))[l8];
    e += 8;
    int sB = (e < end) ? csr[e] : ZROW;
    uint4 b0 = ((const uint4*)(h + (size_t)sB * 64))[l8];
    for (int r = 2; r < rounds; r++) {
        e += 8;
        int sC = (e < end) ? csr[e] : ZROW;
        uint4 c0 = ((const uint4*)(h + (size_t)sC * 64))[l8];
        ACC4(a0)
        a0 = b0; b0 = c0;
    }
    ACC4(a0)
    ACC4(b0)
#pragma unroll
    for (int j = 0; j < 4; j++) {
        acc[j].x += __shfl_xor(acc[j].x, 8);  acc[j].y += __shfl_xor(acc[j].y, 8);
        acc[j].x += __shfl_xor(acc[j].x, 16); acc[j].y += __shfl_xor(acc[j].y, 16);
        acc[j].x += __shfl_xor(acc[j].x, 32); acc[j].y += __shfl_xor(acc[j].y, 32);
    }
    if (oct == 0) {                            // lane l8 holds feats [l8*8, +8)
        int isf32 = flags[0];
        float dd = dinv[d];
        float r[8];
#pragma unroll
        for (int j = 0; j < 4; j++) {
            float bx = isf32 ? ((const float*)bias)[l8 * 8 + 2 * j]
                             : b2f(((const u16*)bias)[l8 * 8 + 2 * j]);
            float by = isf32 ? ((const float*)bias)[l8 * 8 + 2 * j + 1]
                             : b2f(((const u16*)bias)[l8 * 8 + 2 * j + 1]);
            r[2 * j]     = acc[j].x * dd + bx;
            r[2 * j + 1] = acc[j].y * dd + by;
        }
        float4* op = (float4*)(out + (size_t)d * 64) + l8 * 2;
        op[0] = make_float4(r[0], r[1], r[2], r[3]);
        op[1] = make_float4(r[4], r[5], r[6], r[7]);
    }
}

extern "C" void kernel_launch(void* const* d_in, const int* in_sizes, int n_in,
                              void* d_out, int out_size, void* d_ws, size_t ws_size,
                              hipStream_t stream) {
    const void* x  = d_in[0];              // [50000,128] fp32
    const int*  ei = (const int*)d_in[1];  // [2,1600000] int32/int64 (detected)
    const void* W1 = d_in[2];
    const void* b1 = d_in[3];
    const void* W2 = d_in[4];
    const void* b2 = d_in[5];
    float* out = (float*)d_out;            // [50000,64] fp32

    char* ws = (char*)d_ws;
    int*      flags    = (int*)(ws + 0);
    int*      bktcnt   = (int*)(ws + 1024);        // 256 ints (memset to 0)
    int*      deg      = (int*)(ws + 4096);        // 200,000 B
    int*      rowstart = (int*)(ws + 204800);
    float*    dinv     = (float*)(ws + 405504);
    unsigned* pairs    = (unsigned*)(ws + 606208); // 7,340,032 B (dead after k_bucket)
    u16*      csr      = (u16*)(ws + 7946240);     // 3,300,032 B (+16 slack entries)
    u16*      h1       = (u16*)(ws + 11247616);    // 50001*128*2 = 12,800,256 B
    u16*      out1     = (u16*)(ws + 24048640);    // 12,800,000 B
    u16*      h2       = (u16*)(ws + 606208);      // alias pairs: 50001*64*2 = 6,400,128 B

    hipMemsetAsync(bktcnt, 0, NBKT * sizeof(int), stream);
    k_part   <<<(N_TOT + TILE - 1) / TILE, 256, 0, stream>>>(ei, (const unsigned*)x,
                                                             flags, pairs, bktcnt);
    k_bucket <<<NBKT, 256, 0, stream>>>(pairs, bktcnt, rowstart, deg, dinv, csr);

    k_gemm<128, true> <<<(N_NODES + 63) / 64, 256, 0, stream>>>(x, W1, dinv, h1, N_NODES, flags);
    k_agg1<<<N_NODES / 4, 256, 0, stream>>>(h1, csr, rowstart, deg, dinv, b1, out1, flags);
    k_gemm<64, false> <<<(N_NODES + 63) / 64, 256, 0, stream>>>(out1, W2, dinv, h2, N_NODES, flags);
    k_agg2<<<N_NODES / 4, 256, 0, stream>>>(h2, csr, rowstart, deg, dinv, b2, out, flags);
}

// Round 10
// 246.529 us; speedup vs baseline: 1.2102x; 1.0180x over previous
//
#include <hip/hip_runtime.h>
#include <hip/hip_bf16.h>
#include <stdint.h>

#define N_NODES 50000
#define N_EDGES 1600000
#define N_TOT   (N_EDGES + N_NODES)
#define NBKT      256
#define BKT_NODES 196   // 256*196 = 50176 >= 50000
#define BKT_CAP   7168  // mean 6468, sd ~79 -> +8.8 sigma; deterministic input
#define TILE      4096
#define EPT       16    // edges per thread in k_part
#define ZROW      N_NODES   // zero-padding row index in h buffers

typedef unsigned short u16;
typedef __attribute__((ext_vector_type(8))) short short8;
typedef __attribute__((ext_vector_type(4))) float floatx4;

__device__ __forceinline__ float b2f(u16 u) {
    union { unsigned int i; float f; } v; v.i = ((unsigned int)u) << 16; return v.f;
}
__device__ __forceinline__ float asf(unsigned u) {
    union { unsigned int i; float f; } v; v.i = u; return v.f;
}
__device__ __forceinline__ u16 f2b(float f) {
    union { unsigned int i; float f; } v; v.f = f;
    unsigned int r = (v.i + 0x7FFFu + ((v.i >> 16) & 1u)) >> 16;
    return (u16)r;
}

// ---- pass 1: partition edges into 256 dst-buckets (coalesced writes) ----
__global__ __launch_bounds__(256) void k_part(const int* __restrict__ ei,
                                              const unsigned* __restrict__ xw,
                                              int* __restrict__ flags,
                                              unsigned* __restrict__ pairs,
                                              int* __restrict__ bktcnt) {
    __shared__ unsigned pairsL[TILE];
    __shared__ unsigned char bktL[TILE];
    __shared__ int hist[NBKT], incl[NBKT], delta[NBKT];
    __shared__ int zc, pc;
    int tid = threadIdx.x;
    long base = (long)blockIdx.x * TILE;
    hist[tid] = 0;
    if (tid == 0) { zc = 0; pc = 0; }
    __syncthreads();
    // i64 detection: odd 32-bit words of first 256 edge slots all zero iff int64.
    unsigned hw = ((const unsigned*)ei)[2 * tid + 1];
    atomicAdd(&zc, hw == 0 ? 1 : 0);
    if (blockIdx.x == 0) {
        unsigned w = xw[tid];
        int ex = (w >> 7) & 0xFF;
        atomicAdd(&pc, ((ex == 0) || (ex >= 0x60 && ex <= 0x9F)) ? 1 : 0);
    }
    __syncthreads();
    int i64 = zc > 250;
    if (blockIdx.x == 0 && tid == 0) {
        flags[0] = (pc < 160) ? 1 : 0;   // fp32 inputs
        flags[1] = i64;
    }

    int myb[EPT], myrank[EPT]; unsigned myp[EPT];
#pragma unroll
    for (int t = 0; t < EPT; t++) {
        long idx = base + t * 256 + tid;
        int b = -1; unsigned p = 0;
        if (idx < N_TOT) {
            int s, d;
            if (idx < N_EDGES) {
                if (i64) { s = ei[2 * idx]; d = ei[2 * (N_EDGES + idx)]; }
                else     { s = ei[idx];     d = ei[N_EDGES + idx]; }
            } else {
                s = d = (int)(idx - N_EDGES);   // self-loop
            }
            b = d / BKT_NODES;
            p = (unsigned)s | ((unsigned)(d - b * BKT_NODES) << 16);
        }
        myb[t] = b; myp[t] = p;
        myrank[t] = (b >= 0) ? atomicAdd(&hist[b], 1) : 0;
    }
    __syncthreads();

    int tot = hist[tid];
    incl[tid] = tot;
    __syncthreads();
    for (int o = 1; o < NBKT; o <<= 1) {
        int t2 = (tid >= o) ? incl[tid - o] : 0;
        __syncthreads();
        incl[tid] += t2;
        __syncthreads();
    }
    int excl = incl[tid] - tot;
    int gb = atomicAdd(&bktcnt[tid], tot);
    hist[tid]  = excl;
    delta[tid] = tid * BKT_CAP + gb - excl;
    __syncthreads();

#pragma unroll
    for (int t = 0; t < EPT; t++) {
        if (myb[t] >= 0) {
            int slot = hist[myb[t]] + myrank[t];
            pairsL[slot] = myp[t];
            bktL[slot]   = (unsigned char)myb[t];
        }
    }
    __syncthreads();
    int count = incl[NBKT - 1];
    for (int i = tid; i < count; i += 256) {
        int b = bktL[i];
        int pos = delta[b] + i;
        if (pos - b * BKT_CAP < BKT_CAP)
            pairs[pos] = pairsL[i];
    }
}

// ---- pass 2: per bucket -> deg/rowstart/dinv + LDS csr, coalesced out ---
__global__ __launch_bounds__(256) void k_bucket(const unsigned* __restrict__ pairs,
                                                const int* __restrict__ bktcnt,
                                                int* __restrict__ rowstart,
                                                int* __restrict__ deg,
                                                float* __restrict__ dinv,
                                                u16* __restrict__ csr) {
    __shared__ u16 csrL[BKT_CAP];
    __shared__ int degL[NBKT], curL[NBKT], scanT[NBKT];
    int b = blockIdx.x, tid = threadIdx.x;
    int cv = bktcnt[tid];
    scanT[tid] = cv;
    __syncthreads();
    for (int o = 1; o < NBKT; o <<= 1) {
        int t = (tid >= o) ? scanT[tid - o] : 0;
        __syncthreads();
        scanT[tid] += t;
        __syncthreads();
    }
    int cnt  = bktcnt[b];
    int base = scanT[b] - cnt;
    __syncthreads();

    const unsigned* reg = pairs + (size_t)b * BKT_CAP;
    degL[tid] = 0;
    __syncthreads();
    for (int i = tid; i < cnt; i += 256)
        atomicAdd(&degL[reg[i] >> 16], 1);
    __syncthreads();
    int v = degL[tid];
    scanT[tid] = v;
    __syncthreads();
    for (int o = 1; o < NBKT; o <<= 1) {
        int t = (tid >= o) ? scanT[tid - o] : 0;
        __syncthreads();
        scanT[tid] += t;
        __syncthreads();
    }
    int excl = scanT[tid] - v;
    curL[tid] = excl;
    int n = b * BKT_NODES + tid;
    if (tid < BKT_NODES && n < N_NODES) {
        rowstart[n] = base + excl;
        deg[n]      = v;
        dinv[n]     = rsqrtf((float)v);
    }
    __syncthreads();
    for (int i = tid; i < cnt; i += 256) {
        unsigned p = reg[i];
        int slot = atomicAdd(&curL[p >> 16], 1);
        csrL[slot] = (u16)(p & 0xFFFFu);
    }
    __syncthreads();
    for (int i = tid; i < cnt; i += 256)
        csr[base + i] = csrL[i];
}

// ---- GEMM: out[M x NOUT] = (A[M x 128] @ W[128 x NOUT]) * dinv[row] -----
template<int NOUT, bool ADYN>
__global__ __launch_bounds__(256) void k_gemm(const void* __restrict__ A,
                                              const void* __restrict__ W,
                                              const float* __restrict__ dinv,
                                              u16* __restrict__ out, int M,
                                              const int* __restrict__ flags) {
    const int isf32 = flags[0];
    constexpr int LDW = 136;
    __shared__ __align__(16) u16 Wt[NOUT * LDW];
    int tid = threadIdx.x;
    if (blockIdx.x == 0 && tid < NOUT)
        out[(size_t)M * NOUT + tid] = 0;          // zero-pad row
    const float* Wf = (const float*)W;
    const u16*   Wu = (const u16*)W;
    for (int idx = tid; idx < 128 * NOUT; idx += 256) {
        int k = idx / NOUT, n = idx % NOUT;
        Wt[n * LDW + k] = isf32 ? f2b(Wf[idx]) : Wu[idx];
    }
    __syncthreads();

    int wave = tid >> 6, lane = tid & 63;
    int quad = lane >> 4, l16 = lane & 15;
    int r0 = blockIdx.x * 64 + wave * 16;
    int r = r0 + l16; if (r >= M) r = M - 1;

    floatx4 acc[NOUT / 16];
#pragma unroll
    for (int i = 0; i < NOUT / 16; i++) acc[i] = (floatx4)(0.f);

#pragma unroll
    for (int ks = 0; ks < 4; ks++) {
        short8 a;
        if (ADYN && isf32) {
            const float* af = (const float*)A + (size_t)r * 128 + ks * 32 + quad * 8;
            float4 v0 = ((const float4*)af)[0];
            float4 v1 = ((const float4*)af)[1];
            a[0] = (short)f2b(v0.x); a[1] = (short)f2b(v0.y);
            a[2] = (short)f2b(v0.z); a[3] = (short)f2b(v0.w);
            a[4] = (short)f2b(v1.x); a[5] = (short)f2b(v1.y);
            a[6] = (short)f2b(v1.z); a[7] = (short)f2b(v1.w);
        } else {
            a = ((const short8*)((const u16*)A + (size_t)r * 128))[ks * 4 + quad];
        }
#pragma unroll
        for (int nt = 0; nt < NOUT / 16; nt++) {
            const short8* bp = (const short8*)&Wt[(nt * 16 + l16) * LDW + ks * 32 + quad * 8];
            acc[nt] = __builtin_amdgcn_mfma_f32_16x16x32_bf16(a, *bp, acc[nt], 0, 0, 0);
        }
    }
    float sc[4];
#pragma unroll
    for (int j = 0; j < 4; j++) {
        int row = r0 + quad * 4 + j;
        sc[j] = dinv[row < M ? row : 0];
    }
#pragma unroll
    for (int nt = 0; nt < NOUT / 16; nt++) {
#pragma unroll
        for (int j = 0; j < 4; j++) {
            int row = r0 + quad * 4 + j;
            if (row < M)
                out[(size_t)row * NOUT + nt * 16 + l16] = f2b(acc[nt][j] * sc[j]);
        }
    }
}

// accumulate one uint (2 bf16 feats) into a float2 (pk-add friendly)
#define ACCU(u, j) { acc[j].x += asf((u) << 16); acc[j].y += asf((u) & 0xFFFF0000u); }
#define ACC4(q)    { ACCU(q.x,0) ACCU(q.y,1) ACCU(q.z,2) ACCU(q.w,3) }

// ---- Aggregation L1: 16-lane groups, fully-contiguous 256B row loads,
// depth-4 pipeline (4 rows in flight/wave), uniform rounds, zero-row pad.
__global__ __launch_bounds__(256) void k_agg1(const u16* __restrict__ h,
                                              const u16* __restrict__ csr,
                                              const int* __restrict__ rowstart,
                                              const int* __restrict__ deg,
                                              const float* __restrict__ dinv,
                                              const void* __restrict__ bias,
                                              u16* __restrict__ out,
                                              const int* __restrict__ flags) {
    int wave = threadIdx.x >> 6, lane = threadIdx.x & 63;
    int d = blockIdx.x * 4 + wave;               // 12500 blocks * 4 = exact
    int grp = lane >> 4, l16 = lane & 15;
    int start = rowstart[d], dg = deg[d], end = start + dg;
    int rounds = (dg + 3) >> 2;                  // wave-uniform
    const uint4* hb = (const uint4*)h;           // row s: base index s*16
    float2 acc[4];
#pragma unroll
    for (int j = 0; j < 4; j++) acc[j] = make_float2(0.f, 0.f);

    int e0 = start + grp;
    int s;
    uint4 q0, q1, q2, q3;
    s = (e0      < end) ? csr[e0]      : ZROW; q0 = hb[(size_t)s * 16 + l16];
    s = (e0 + 4  < end) ? csr[e0 + 4]  : ZROW; q1 = hb[(size_t)s * 16 + l16];
    s = (e0 + 8  < end) ? csr[e0 + 8]  : ZROW; q2 = hb[(size_t)s * 16 + l16];
    s = (e0 + 12 < end) ? csr[e0 + 12] : ZROW; q3 = hb[(size_t)s * 16 + l16];
    int r = 4;
    for (; r + 3 < rounds; r += 4) {             // 4x unroll: no reg rotation
        int e = e0 + 4 * r;
        ACC4(q0) s = (e      < end) ? csr[e]      : ZROW; q0 = hb[(size_t)s * 16 + l16];
        ACC4(q1) s = (e + 4  < end) ? csr[e + 4]  : ZROW; q1 = hb[(size_t)s * 16 + l16];
        ACC4(q2) s = (e + 8  < end) ? csr[e + 8]  : ZROW; q2 = hb[(size_t)s * 16 + l16];
        ACC4(q3) s = (e + 12 < end) ? csr[e + 12] : ZROW; q3 = hb[(size_t)s * 16 + l16];
    }
    for (; r < rounds; r++) {                    // <=3 rotations
        int e = e0 + 4 * r;
        ACC4(q0) s = (e < end) ? csr[e] : ZROW;
        q0 = q1; q1 = q2; q2 = q3; q3 = hb[(size_t)s * 16 + l16];
    }
    ACC4(q0) ACC4(q1) ACC4(q2) ACC4(q3)
#pragma unroll
    for (int j = 0; j < 4; j++) {                // reduce across 4 groups
        acc[j].x += __shfl_xor(acc[j].x, 16); acc[j].y += __shfl_xor(acc[j].y, 16);
        acc[j].x += __shfl_xor(acc[j].x, 32); acc[j].y += __shfl_xor(acc[j].y, 32);
    }
    if (grp == 0) {                              // lane l16 holds feats [l16*8,+8)
        int isf32 = flags[0];
        float dd = dinv[d];
        u16 r8[8];
#pragma unroll
        for (int j = 0; j < 4; j++) {
            float bx = isf32 ? ((const float*)bias)[l16 * 8 + 2 * j]
                             : b2f(((const u16*)bias)[l16 * 8 + 2 * j]);
            float by = isf32 ? ((const float*)bias)[l16 * 8 + 2 * j + 1]
                             : b2f(((const u16*)bias)[l16 * 8 + 2 * j + 1]);
            float vx = acc[j].x * dd + bx;
            float vy = acc[j].y * dd + by;
            r8[2 * j]     = f2b(vx > 0.f ? vx : 0.f);
            r8[2 * j + 1] = f2b(vy > 0.f ? vy : 0.f);
        }
        uint4 o;
        o.x = r8[0] | ((unsigned)r8[1] << 16); o.y = r8[2] | ((unsigned)r8[3] << 16);
        o.z = r8[4] | ((unsigned)r8[5] << 16); o.w = r8[6] | ((unsigned)r8[7] << 16);
        ((uint4*)(out + (size_t)d * 128))[l16] = o;
    }
}

// ---- Aggregation L2: 8-lane groups (contiguous 128B rows), depth-3 ------
__global__ __launch_bounds__(256) void k_agg2(const u16* __restrict__ h,
                                              const u16* __restrict__ csr,
                                              const int* __restrict__ rowstart,
                                              const int* __restrict__ deg,
                                              const float* __restrict__ dinv,
                                              const void* __restrict__ bias,
                                              float* __restrict__ out,
                                              const int* __restrict__ flags) {
    int wave = threadIdx.x >> 6, lane = threadIdx.x & 63;
    int d = blockIdx.x * 4 + wave;
    int oct = lane >> 3, l8 = lane & 7;
    int start = rowstart[d], dg = deg[d], end = start + dg;
    int rounds = (dg + 7) >> 3;
    const uint4* hb = (const uint4*)h;           // row s: base index s*8
    float2 acc[4];
#pragma unroll
    for (int j = 0; j < 4; j++) acc[j] = make_float2(0.f, 0.f);

    int e0 = start + oct;
    int s;
    uint4 q0, q1, q2;
    s = (e0      < end) ? csr[e0]      : ZROW; q0 = hb[(size_t)s * 8 + l8];
    s = (e0 + 8  < end) ? csr[e0 + 8]  : ZROW; q1 = hb[(size_t)s * 8 + l8];
    s = (e0 + 16 < end) ? csr[e0 + 16] : ZROW; q2 = hb[(size_t)s * 8 + l8];
    int r = 3;
    for (; r + 2 < rounds; r += 3) {
        int e = e0 + 8 * r;
        ACC4(q0) s = (e      < end) ? csr[e]      : ZROW; q0 = hb[(size_t)s * 8 + l8];
        ACC4(q1) s = (e + 8  < end) ? csr[e + 8]  : ZROW; q1 = hb[(size_t)s * 8 + l8];
        ACC4(q2) s = (e + 16 < end) ? csr[e + 16] : ZROW; q2 = hb[(size_t)s * 8 + l8];
    }
    for (; r < rounds; r++) {
        int e = e0 + 8 * r;
        ACC4(q0) s = (e < end) ? csr[e] : ZROW;
        q0 = q1; q1 = q2; q2 = hb[(size_t)s * 8 + l8];
    }
    ACC4(q0) ACC4(q1) ACC4(q2)
#pragma unroll
    for (int j = 0; j < 4; j++) {
        acc[j].x += __shfl_xor(acc[j].x, 8);  acc[j].y += __shfl_xor(acc[j].y, 8);
        acc[j].x += __shfl_xor(acc[j].x, 16); acc[j].y += __shfl_xor(acc[j].y, 16);
        acc[j].x += __shfl_xor(acc[j].x, 32); acc[j].y += __shfl_xor(acc[j].y, 32);
    }
    if (oct == 0) {                            // lane l8 holds feats [l8*8, +8)
        int isf32 = flags[0];
        float dd = dinv[d];
        float r8[8];
#pragma unroll
        for (int j = 0; j < 4; j++) {
            float bx = isf32 ? ((const float*)bias)[l8 * 8 + 2 * j]
                             : b2f(((const u16*)bias)[l8 * 8 + 2 * j]);
            float by = isf32 ? ((const float*)bias)[l8 * 8 + 2 * j + 1]
                             : b2f(((const u16*)bias)[l8 * 8 + 2 * j + 1]);
            r8[2 * j]     = acc[j].x * dd + bx;
            r8[2 * j + 1] = acc[j].y * dd + by;
        }
        float4* op = (float4*)(out + (size_t)d * 64) + l8 * 2;
        op[0] = make_float4(r8[0], r8[1], r8[2], r8[3]);
        op[1] = make_float4(r8[4], r8[5], r8[6], r8[7]);
    }
}

extern "C" void kernel_launch(void* const* d_in, const int* in_sizes, int n_in,
                              void* d_out, int out_size, void* d_ws, size_t ws_size,
                              hipStream_t stream) {
    const void* x  = d_in[0];              // [50000,128] fp32
    const int*  ei = (const int*)d_in[1];  // [2,1600000] int32/int64 (detected)
    const void* W1 = d_in[2];
    const void* b1 = d_in[3];
    const void* W2 = d_in[4];
    const void* b2 = d_in[5];
    float* out = (float*)d_out;            // [50000,64] fp32

    char* ws = (char*)d_ws;
    int*      flags    = (int*)(ws + 0);
    int*      bktcnt   = (int*)(ws + 1024);        // 256 ints (memset to 0)
    int*      deg      = (int*)(ws + 4096);
    int*      rowstart = (int*)(ws + 204800);
    float*    dinv     = (float*)(ws + 405504);
    unsigned* pairs    = (unsigned*)(ws + 606208); // 7,340,032 B (dead after k_bucket)
    u16*      csr      = (u16*)(ws + 7946240);     // 3,300,032 B
    u16*      h1       = (u16*)(ws + 11247616);    // 50001*128*2 = 12,800,256 B
    u16*      out1     = (u16*)(ws + 24048640);    // 12,800,000 B
    u16*      h2       = (u16*)(ws + 606208);      // alias pairs: 50001*64*2 B

    hipMemsetAsync(bktcnt, 0, NBKT * sizeof(int), stream);
    k_part   <<<(N_TOT + TILE - 1) / TILE, 256, 0, stream>>>(ei, (const unsigned*)x,
                                                             flags, pairs, bktcnt);
    k_bucket <<<NBKT, 256, 0, stream>>>(pairs, bktcnt, rowstart, deg, dinv, csr);

    k_gemm<128, true> <<<(N_NODES + 63) / 64, 256, 0, stream>>>(x, W1, dinv, h1, N_NODES, flags);
    k_agg1<<<N_NODES / 4, 256, 0, stream>>>(h1, csr, rowstart, deg, dinv, b1, out1, flags);
    k_gemm<64, false> <<<(N_NODES + 63) / 64, 256, 0, stream>>>(out1, W2, dinv, h2, N_NODES, flags);
    k_agg2<<<N_NODES / 4, 256, 0, stream>>>(h2, csr, rowstart, deg, dinv, b2, out, flags);
}